// Round 8
// baseline (278.493 us; speedup 1.0000x reference)
//
#include <hip/hip_runtime.h>
#include <hip/hip_bf16.h>

// B=2, S=2048, D=1024, H=16, DK=64. Inputs fp32 (+ int32 tril mask -> causal
// analytically). Output fp32.
// R8: proj GEMMs rewritten on mfma_f32_32x32x16_bf16 with FRAG-MAJOR LDS:
// each 32x16 fragment = 1KB contiguous block (one async16 to stage, one
// immediate-offset ds_read_b128 to load, zero swizzle VALU, zero conflicts).
// Halves MFMA instr count per MAC. attn (XCD-grouped) and cvt unchanged.

#define B_ 2
#define S_ 2048
#define D_ 1024
#define H_ 16
#define DK_ 64
#define SZX (4096 * 1024)
#define SZW (1024 * 1024)

typedef __attribute__((ext_vector_type(8))) short short8;     // 8 x bf16 MFMA A/B frag
typedef __attribute__((ext_vector_type(4))) float f32x4;      // 16x16 C/D frag
typedef __attribute__((ext_vector_type(16))) float f32x16;    // 32x32 C/D frag

using bf16 = __hip_bfloat16;

__device__ __forceinline__ short8 load8(const bf16* p) {
    return *reinterpret_cast<const short8*>(p);
}

__device__ __forceinline__ f32x4 mfma16(short8 a, short8 b, f32x4 c) {
    return __builtin_amdgcn_mfma_f32_16x16x32_bf16(a, b, c, 0, 0, 0);
}

__device__ __forceinline__ f32x16 mfma32(short8 a, short8 b, f32x16 c) {
    return __builtin_amdgcn_mfma_f32_32x32x16_bf16(a, b, c, 0, 0, 0);
}

// async global->LDS 16B: each lane writes (wave-uniform base) + lane*16.
// Global side may be a per-lane scatter (verified R5-R7).
__device__ __forceinline__ void async16(const bf16* g, bf16* l) {
    __builtin_amdgcn_global_load_lds(
        (const __attribute__((address_space(1))) void*)g,
        (__attribute__((address_space(3))) void*)l, 16, 0, 0);
}

// fp32 -> bf16 RNE (finite inputs).
__device__ __forceinline__ short bf16rne(float f) {
    unsigned u = __float_as_uint(f);
    return (short)((u + 0x7FFFu + ((u >> 16) & 1u)) >> 16);
}

// ---------------- one-time fp32 -> bf16 conversion ----------------
struct CvtArgs {
    const float* src[7];
    bf16* dst[7];
};

__global__ __launch_bounds__(256) void cvt_kernel(CvtArgs a) {
    const long long e = ((long long)blockIdx.x * 256 + threadIdx.x) * 8;
    int t; long long off;
    if (e < 3LL * SZX) { t = (int)(e >> 22); off = e & (SZX - 1); }
    else { const long long e2 = e - 3LL * SZX; t = 3 + (int)(e2 >> 20); off = e2 & (SZW - 1); }
    const float4 f0 = *reinterpret_cast<const float4*>(a.src[t] + off);
    const float4 f1 = *reinterpret_cast<const float4*>(a.src[t] + off + 4);
    short8 o;
    o[0] = bf16rne(f0.x); o[1] = bf16rne(f0.y); o[2] = bf16rne(f0.z); o[3] = bf16rne(f0.w);
    o[4] = bf16rne(f1.x); o[5] = bf16rne(f1.y); o[6] = bf16rne(f1.z); o[7] = bf16rne(f1.w);
    *reinterpret_cast<short8*>((short*)a.dst[t] + off) = o;
}

// ---------------- projection GEMM: 32x32x16 MFMA, frag-major LDS ----------------
// Y = X(4096xD) @ W(NxD)^T + bias. Tile BM x 128, BK=64, 4 waves.
// Fragment (sub,kk) = rows [sub*32,+32) x k [kk*16,+16): 1KB contiguous LDS,
// element (m=lane&31, k=(lane>>5)*8+j) at lane*16B. One async16 stages it;
// one ds_read_b128 (immediate offset) loads it.
// A-op: A[m=lane&31][k=(lane>>5)*8+j]; B-op: B[n=lane&31][k=(lane>>5)*8+j];
// C/D: col=lane&31, row=(reg&3)+8*(reg>>2)+4*(lane>>5)   (m74/m101).
// mode 0/1: bf16 (B,H,S,DK)  mode 2: bf16 (B,H,DK,S)  mode 3: fp32 row-major
struct ProjArgs {
    const bf16* X[3]; const bf16* W[3]; const float* bias[3]; void* Y[3]; int mode[3];
};

template <int BM>
__global__ __launch_bounds__(256) void proj_kernel(ProjArgs a) {
    constexpr int MSUB = BM / 32;      // A 32-row subtiles per block (4 or 2)
    constexpr int WM   = MSUB / 2;     // m-subtiles per wave (2 or 1)

    const int z = blockIdx.z;
    const bf16* __restrict__ X = a.X[z];
    const bf16* __restrict__ W = a.W[z];
    const float* __restrict__ bias = a.bias[z];
    const int mode = a.mode[z];

    __shared__ __align__(16) bf16 lA[MSUB * 4 * 512];   // frag-major
    __shared__ __align__(16) bf16 lB[16 * 512];

    const int tid  = threadIdx.x;
    const int wv   = tid >> 6;
    const int lane = tid & 63;
    const int l31  = lane & 31;
    const int khi  = lane >> 5;        // k-group (0/1)
    const int m0   = blockIdx.x * BM;
    const int n0   = blockIdx.y * 128;

    // precomputed per-lane global row bases for staging
    const bf16* gA[MSUB];
    #pragma unroll
    for (int s = 0; s < MSUB; ++s) {
        const int fa = wv * MSUB + s;                 // frag id
        gA[s] = X + (size_t)(m0 + (fa >> 2) * 32 + l31) * D_ + (fa & 3) * 16 + khi * 8;
    }
    const bf16* gB = W + (size_t)(n0 + wv * 32 + l31) * D_ + khi * 8;

    f32x16 acc[WM][2] = {};

    #pragma unroll 1
    for (int k0 = 0; k0 < D_; k0 += 64) {
        #pragma unroll
        for (int s = 0; s < MSUB; ++s)
            async16(gA[s] + k0, &lA[(wv * MSUB + s) * 512]);
        #pragma unroll
        for (int s = 0; s < 4; ++s)
            async16(gB + k0 + s * 16, &lB[(wv * 4 + s) * 512]);
        __syncthreads();

        #pragma unroll
        for (int kk = 0; kk < 4; ++kk) {
            short8 af[WM], bfr[2];
            #pragma unroll
            for (int mi = 0; mi < WM; ++mi)
                af[mi] = load8(&lA[(((wv & 1) * WM + mi) * 4 + kk) * 512 + lane * 8]);
            #pragma unroll
            for (int ni = 0; ni < 2; ++ni)
                bfr[ni] = load8(&lB[(((wv >> 1) * 2 + ni) * 4 + kk) * 512 + lane * 8]);
            #pragma unroll
            for (int mi = 0; mi < WM; ++mi)
                #pragma unroll
                for (int ni = 0; ni < 2; ++ni)
                    acc[mi][ni] = mfma32(af[mi], bfr[ni], acc[mi][ni]);
        }
        __syncthreads();
    }

    #pragma unroll
    for (int ni = 0; ni < 2; ++ni) {
        const int col = n0 + (wv >> 1) * 64 + ni * 32 + l31;
        const float bv = bias[col];
        const int h = col >> 6, d = col & 63;
        #pragma unroll
        for (int mi = 0; mi < WM; ++mi) {
            const int rb = m0 + ((wv & 1) * WM + mi) * 32 + 4 * khi;
            #pragma unroll
            for (int reg = 0; reg < 16; ++reg) {
                const int m = rb + (reg & 3) + 8 * (reg >> 2);
                const float val = acc[mi][ni][reg] + bv;
                if (mode == 3) {
                    ((float*)a.Y[z])[(size_t)m * D_ + col] = val;
                } else {
                    bf16* Y = (bf16*)a.Y[z];
                    const bf16 o = __float2bfloat16(val);
                    const int b  = m >> 11;
                    const int s  = m & (S_ - 1);
                    const int bh = b * H_ + h;
                    if (mode == 2) Y[((size_t)bh * DK_ + d) * S_ + s] = o;
                    else           Y[((size_t)bh * S_ + s) * DK_ + d] = o;
                }
            }
        }
    }
}

// ---------------- flash attention, causal, LDS-staged K/V, XCD-grouped ----------------
// (unchanged from R7 — attn measured <62us there)
__global__ __launch_bounds__(256) void attn_kernel(
    const bf16* __restrict__ Qb, const bf16* __restrict__ Kb,
    const bf16* __restrict__ Vt, bf16* __restrict__ ctx)
{
    __shared__ __align__(16) bf16 Kt[64 * 64];
    __shared__ __align__(16) bf16 Vl[64 * 64];
    __shared__ __align__(16) bf16 lds_p[4][16][72];

    const int tid  = threadIdx.x;
    const int wv   = tid >> 6;
    const int lane = tid & 63;
    const int quad = lane >> 4;
    const int l16  = lane & 15;

    const int bx = blockIdx.x;
    const int bh = (bx & 7) * 4 + ((bx >> 3) & 3);
    const int m  = 31 - (bx >> 5);            // q-tile index, heavy first
    const int q0 = m * 64;
    const int qr = q0 + wv * 16;

    const bf16* Qh = Qb + (size_t)bh * (S_ * DK_);
    const bf16* Kh = Kb + (size_t)bh * (S_ * DK_);
    const bf16* Vh = Vt + (size_t)bh * (DK_ * S_);

    const float c = 0.18033688011112042f;     // log2(e)/sqrt(DK)
    const short8 ones = {16256, 16256, 16256, 16256, 16256, 16256, 16256, 16256};

    const int srow  = wv * 8 + (lane >> 3);
    const int sunit = (lane & 7) ^ ((lane >> 3) & 7);

    const short8 qa0 = load8(Qh + (qr + l16) * DK_ + quad * 8);
    const short8 qa1 = load8(Qh + (qr + l16) * DK_ + 32 + quad * 8);

    f32x4 cacc[4] = {};
    f32x4 lsum = {};

    for (int jt = 0; jt <= m; ++jt) {
        const int j0 = jt * 64;

        #pragma unroll
        for (int cc = 0; cc < 2; ++cc) {
            const int r = cc * 32 + srow;
            async16(Kh + (size_t)(j0 + r) * DK_ + sunit * 8, &Kt[(cc * 32 + wv * 8) * 64]);
            async16(Vh + (size_t)r * S_ + j0 + sunit * 8,    &Vl[(cc * 32 + wv * 8) * 64]);
        }
        __syncthreads();

        short8 kb[4][2], vb[4][2];
        #pragma unroll
        for (int t = 0; t < 4; ++t)
            #pragma unroll
            for (int kh = 0; kh < 2; ++kh) {
                const int u = ((kh * 4 + quad) ^ (l16 & 7)) * 8;
                kb[t][kh] = load8(&Kt[(t * 16 + l16) * 64 + u]);
                vb[t][kh] = load8(&Vl[(t * 16 + l16) * 64 + u]);
            }

        f32x4 s[4];
        #pragma unroll
        for (int t = 0; t < 4; ++t) {
            f32x4 zz = {};
            zz = mfma16(qa0, kb[t][0], zz);
            s[t] = mfma16(qa1, kb[t][1], zz);
        }

        if (jt < m) {
            #pragma unroll
            for (int r = 0; r < 4; ++r)
                #pragma unroll
                for (int t = 0; t < 4; ++t)
                    lds_p[wv][quad * 4 + r][t * 16 + l16] =
                        __float2bfloat16(exp2f(c * s[t][r]));
        } else {
            #pragma unroll
            for (int r = 0; r < 4; ++r) {
                const int row = qr + quad * 4 + r;
                #pragma unroll
                for (int t = 0; t < 4; ++t) {
                    const float p = (j0 + t * 16 + l16 <= row) ? exp2f(c * s[t][r]) : 0.f;
                    lds_p[wv][quad * 4 + r][t * 16 + l16] = __float2bfloat16(p);
                }
            }
        }

        asm volatile("s_waitcnt lgkmcnt(0)" ::: "memory");
        const short8 pa0 = load8(&lds_p[wv][l16][quad * 8]);
        const short8 pa1 = load8(&lds_p[wv][l16][32 + quad * 8]);

        #pragma unroll
        for (int dt = 0; dt < 4; ++dt) {
            cacc[dt] = mfma16(pa0, vb[dt][0], cacc[dt]);
            cacc[dt] = mfma16(pa1, vb[dt][1], cacc[dt]);
        }
        lsum = mfma16(pa0, ones, lsum);
        lsum = mfma16(pa1, ones, lsum);

        __syncthreads();
    }

    const int bb = bh >> 4, hh = bh & 15;
    #pragma unroll
    for (int r = 0; r < 4; ++r) {
        const float inv = 1.0f / lsum[r];
        const int row = qr + quad * 4 + r;
        bf16* orow = ctx + (size_t)(bb * S_ + row) * D_ + hh * DK_;
        #pragma unroll
        for (int dt = 0; dt < 4; ++dt)
            orow[dt * 16 + l16] = __float2bfloat16(cacc[dt][r] * inv);
    }
}

extern "C" void kernel_launch(void* const* d_in, const int* in_sizes, int n_in,
                              void* d_out, int out_size, void* d_ws, size_t ws_size,
                              hipStream_t stream) {
    (void)in_sizes; (void)n_in; (void)out_size; (void)ws_size;
    const float* q  = (const float*)d_in[0];
    const float* k  = (const float*)d_in[1];
    const float* v  = (const float*)d_in[2];
    // d_in[3] = mask (int32 tril) -> causal analytically
    const float* wq = (const float*)d_in[4];
    const float* bq = (const float*)d_in[5];
    const float* wk = (const float*)d_in[6];
    const float* bk = (const float*)d_in[7];
    const float* wv = (const float*)d_in[8];
    const float* bv = (const float*)d_in[9];
    const float* wo = (const float*)d_in[10];
    const float* bo = (const float*)d_in[11];

    bf16* base = (bf16*)d_ws;
    bf16* Qb  = base;                         // (B,H,S,DK)
    bf16* Kb  = base + 1 * (size_t)SZX;
    bf16* Vt  = base + 2 * (size_t)SZX;       // (B,H,DK,S)
    bf16* ctx = base + 3 * (size_t)SZX;       // (B,S,D)
    bf16* xq  = base + 4 * (size_t)SZX;
    bf16* xk  = base + 5 * (size_t)SZX;
    bf16* xv  = base + 6 * (size_t)SZX;
    bf16* wqb = base + 7 * (size_t)SZX;
    bf16* wkb = wqb + 1 * (size_t)SZW;
    bf16* wvb = wqb + 2 * (size_t)SZW;
    bf16* wob = wqb + 3 * (size_t)SZW;

    CvtArgs ca;
    ca.src[0] = q;  ca.src[1] = k;  ca.src[2] = v;
    ca.src[3] = wq; ca.src[4] = wk; ca.src[5] = wv; ca.src[6] = wo;
    ca.dst[0] = xq;  ca.dst[1] = xk;  ca.dst[2] = xv;
    ca.dst[3] = wqb; ca.dst[4] = wkb; ca.dst[5] = wvb; ca.dst[6] = wob;
    cvt_kernel<<<8192, 256, 0, stream>>>(ca);

    ProjArgs pa;
    pa.X[0] = xq;  pa.X[1] = xk;  pa.X[2] = xv;
    pa.W[0] = wqb; pa.W[1] = wkb; pa.W[2] = wvb;
    pa.bias[0] = bq; pa.bias[1] = bk; pa.bias[2] = bv;
    pa.Y[0] = Qb; pa.Y[1] = Kb; pa.Y[2] = Vt;
    pa.mode[0] = 0; pa.mode[1] = 1; pa.mode[2] = 2;
    proj_kernel<128><<<dim3(32, 8, 3), 256, 0, stream>>>(pa);

    attn_kernel<<<dim3(1024), 256, 0, stream>>>(Qb, Kb, Vt, ctx);

    ProjArgs po;
    po.X[0] = ctx; po.W[0] = wob; po.bias[0] = bo; po.Y[0] = d_out; po.mode[0] = 3;
    po.X[1] = ctx; po.W[1] = wob; po.bias[1] = bo; po.Y[1] = d_out; po.mode[1] = 3;
    po.X[2] = ctx; po.W[2] = wob; po.bias[2] = bo; po.Y[2] = d_out; po.mode[2] = 3;
    proj_kernel<64><<<dim3(64, 8, 1), 256, 0, stream>>>(po);
}

// Round 9
// 248.286 us; speedup vs baseline: 1.1217x; 1.1217x over previous
//
#include <hip/hip_runtime.h>
#include <hip/hip_bf16.h>

// B=2, S=2048, D=1024, H=16, DK=64. Inputs fp32 (+ int32 tril mask -> causal
// analytically). Output fp32.
// R9: proj = 32x32x16 MFMA (R8-verified C/D layout) + R7's row-major swizzled
// LDS staging (8 full cache lines per async16 -- R8's frag-major staging
// scattered 32 lines/instr and regressed). Smaller tiles for occupancy:
// QKV 128x64 (1536 blocks, ~5/CU), out-proj 64x64 (1024 blocks, 4/CU).
// attn (XCD-grouped, LDS-staged) and cvt unchanged.

#define B_ 2
#define S_ 2048
#define D_ 1024
#define H_ 16
#define DK_ 64
#define SZX (4096 * 1024)
#define SZW (1024 * 1024)

typedef __attribute__((ext_vector_type(8))) short short8;     // 8 x bf16 MFMA A/B frag
typedef __attribute__((ext_vector_type(4))) float f32x4;      // 16x16 C/D frag
typedef __attribute__((ext_vector_type(16))) float f32x16;    // 32x32 C/D frag

using bf16 = __hip_bfloat16;

__device__ __forceinline__ short8 load8(const bf16* p) {
    return *reinterpret_cast<const short8*>(p);
}

__device__ __forceinline__ f32x4 mfma16(short8 a, short8 b, f32x4 c) {
    return __builtin_amdgcn_mfma_f32_16x16x32_bf16(a, b, c, 0, 0, 0);
}

__device__ __forceinline__ f32x16 mfma32(short8 a, short8 b, f32x16 c) {
    return __builtin_amdgcn_mfma_f32_32x32x16_bf16(a, b, c, 0, 0, 0);
}

// async global->LDS 16B: each lane writes (wave-uniform base) + lane*16.
__device__ __forceinline__ void async16(const bf16* g, bf16* l) {
    __builtin_amdgcn_global_load_lds(
        (const __attribute__((address_space(1))) void*)g,
        (__attribute__((address_space(3))) void*)l, 16, 0, 0);
}

// fp32 -> bf16 RNE (finite inputs).
__device__ __forceinline__ short bf16rne(float f) {
    unsigned u = __float_as_uint(f);
    return (short)((u + 0x7FFFu + ((u >> 16) & 1u)) >> 16);
}

// ---------------- one-time fp32 -> bf16 conversion ----------------
struct CvtArgs {
    const float* src[7];
    bf16* dst[7];
};

__global__ __launch_bounds__(256) void cvt_kernel(CvtArgs a) {
    const long long e = ((long long)blockIdx.x * 256 + threadIdx.x) * 8;
    int t; long long off;
    if (e < 3LL * SZX) { t = (int)(e >> 22); off = e & (SZX - 1); }
    else { const long long e2 = e - 3LL * SZX; t = 3 + (int)(e2 >> 20); off = e2 & (SZW - 1); }
    const float4 f0 = *reinterpret_cast<const float4*>(a.src[t] + off);
    const float4 f1 = *reinterpret_cast<const float4*>(a.src[t] + off + 4);
    short8 o;
    o[0] = bf16rne(f0.x); o[1] = bf16rne(f0.y); o[2] = bf16rne(f0.z); o[3] = bf16rne(f0.w);
    o[4] = bf16rne(f1.x); o[5] = bf16rne(f1.y); o[6] = bf16rne(f1.z); o[7] = bf16rne(f1.w);
    *reinterpret_cast<short8*>((short*)a.dst[t] + off) = o;
}

// ---------------- projection GEMM: 32x32x16 MFMA, row-major swizzled LDS ----------------
// Y = X(4096xD) @ W(NxD)^T + bias. Tile BM x BN, BK=64, 4 waves in a
// (BM/WTM) x (BN/WTN) = 2x2 arrangement, wave tile WTM x WTN.
// LDS rows = 64 elems (128B); 16B unit u of row r stored at position u^(r&7).
// Staging: one async16 = 8 contiguous rows x full 128B line (R7-verified).
// A-op: A[m=lane&31][k=(lane>>5)*8+j]; B-op likewise.
// C/D: col=lane&31, row=(reg&3)+8*(reg>>2)+4*(lane>>5)  (R8 end-to-end verified).
// mode 0/1: bf16 (B,H,S,DK)  mode 2: bf16 (B,H,DK,S)  mode 3: fp32 row-major
struct ProjArgs {
    const bf16* X[3]; const bf16* W[3]; const float* bias[3]; void* Y[3]; int mode[3];
};

template <int BM, int BN>
__global__ __launch_bounds__(256) void proj_kernel(ProjArgs a) {
    constexpr int WTM = BM / 2, WTN = BN / 2;   // wave tile
    constexpr int WM = WTM / 32, WN = WTN / 32; // 32x32 frags per wave

    const int z = blockIdx.z;
    const bf16* __restrict__ X = a.X[z];
    const bf16* __restrict__ W = a.W[z];
    const float* __restrict__ bias = a.bias[z];
    const int mode = a.mode[z];

    __shared__ __align__(16) bf16 lA[BM * 64];
    __shared__ __align__(16) bf16 lB[BN * 64];

    const int tid  = threadIdx.x;
    const int wv   = tid >> 6;
    const int lane = tid & 63;
    const int l31  = lane & 31;
    const int khi  = lane >> 5;
    const int r7   = l31 & 7;
    const int m0   = blockIdx.x * BM;
    const int n0   = blockIdx.y * BN;

    // staging: wave wv covers A rows [wv*(BM/4), +BM/4) and B rows [wv*(BN/4), +BN/4)
    const int srow  = lane >> 3;
    const int sunit = (lane & 7) ^ (srow & 7);
    const bf16* gA = X + (size_t)(m0 + wv * (BM / 4) + srow) * D_ + sunit * 8;
    const bf16* gB = W + (size_t)(n0 + wv * (BN / 4) + srow) * D_ + sunit * 8;

    f32x16 acc[WM][WN] = {};

    #pragma unroll 1
    for (int k0 = 0; k0 < D_; k0 += 64) {
        #pragma unroll
        for (int cc = 0; cc < BM / 32; ++cc)
            async16(gA + (size_t)cc * 8 * D_ + k0, &lA[(wv * (BM / 4) + cc * 8) * 64]);
        #pragma unroll
        for (int cc = 0; cc < BN / 32; ++cc)
            async16(gB + (size_t)cc * 8 * D_ + k0, &lB[(wv * (BN / 4) + cc * 8) * 64]);
        __syncthreads();

        #pragma unroll
        for (int kk = 0; kk < 4; ++kk) {
            const int up = ((kk * 2 + khi) ^ r7) * 8;   // swizzled 16B-unit offset
            short8 af[WM], bfr[WN];
            #pragma unroll
            for (int mi = 0; mi < WM; ++mi)
                af[mi] = load8(&lA[((wv & 1) * WTM + mi * 32 + l31) * 64 + up]);
            #pragma unroll
            for (int ni = 0; ni < WN; ++ni)
                bfr[ni] = load8(&lB[((wv >> 1) * WTN + ni * 32 + l31) * 64 + up]);
            #pragma unroll
            for (int mi = 0; mi < WM; ++mi)
                #pragma unroll
                for (int ni = 0; ni < WN; ++ni)
                    acc[mi][ni] = mfma32(af[mi], bfr[ni], acc[mi][ni]);
        }
        __syncthreads();
    }

    #pragma unroll
    for (int ni = 0; ni < WN; ++ni) {
        const int col = n0 + (wv >> 1) * WTN + ni * 32 + l31;
        const float bv = bias[col];
        const int h = col >> 6, d = col & 63;
        #pragma unroll
        for (int mi = 0; mi < WM; ++mi) {
            const int rb = m0 + (wv & 1) * WTM + mi * 32 + 4 * khi;
            #pragma unroll
            for (int reg = 0; reg < 16; ++reg) {
                const int m = rb + (reg & 3) + 8 * (reg >> 2);
                const float val = acc[mi][ni][reg] + bv;
                if (mode == 3) {
                    ((float*)a.Y[z])[(size_t)m * D_ + col] = val;
                } else {
                    bf16* Y = (bf16*)a.Y[z];
                    const bf16 o = __float2bfloat16(val);
                    const int b  = m >> 11;
                    const int s  = m & (S_ - 1);
                    const int bh = b * H_ + h;
                    if (mode == 2) Y[((size_t)bh * DK_ + d) * S_ + s] = o;
                    else           Y[((size_t)bh * S_ + s) * DK_ + d] = o;
                }
            }
        }
    }
}

// ---------------- flash attention, causal, LDS-staged K/V, XCD-grouped ----------------
// (unchanged from R7: <62us, FETCH fixed by XCD grouping)
__global__ __launch_bounds__(256) void attn_kernel(
    const bf16* __restrict__ Qb, const bf16* __restrict__ Kb,
    const bf16* __restrict__ Vt, bf16* __restrict__ ctx)
{
    __shared__ __align__(16) bf16 Kt[64 * 64];
    __shared__ __align__(16) bf16 Vl[64 * 64];
    __shared__ __align__(16) bf16 lds_p[4][16][72];

    const int tid  = threadIdx.x;
    const int wv   = tid >> 6;
    const int lane = tid & 63;
    const int quad = lane >> 4;
    const int l16  = lane & 15;

    const int bx = blockIdx.x;
    const int bh = (bx & 7) * 4 + ((bx >> 3) & 3);
    const int m  = 31 - (bx >> 5);            // q-tile index, heavy first
    const int q0 = m * 64;
    const int qr = q0 + wv * 16;

    const bf16* Qh = Qb + (size_t)bh * (S_ * DK_);
    const bf16* Kh = Kb + (size_t)bh * (S_ * DK_);
    const bf16* Vh = Vt + (size_t)bh * (DK_ * S_);

    const float c = 0.18033688011112042f;     // log2(e)/sqrt(DK)
    const short8 ones = {16256, 16256, 16256, 16256, 16256, 16256, 16256, 16256};

    const int srow  = wv * 8 + (lane >> 3);
    const int sunit = (lane & 7) ^ ((lane >> 3) & 7);

    const short8 qa0 = load8(Qh + (qr + l16) * DK_ + quad * 8);
    const short8 qa1 = load8(Qh + (qr + l16) * DK_ + 32 + quad * 8);

    f32x4 cacc[4] = {};
    f32x4 lsum = {};

    for (int jt = 0; jt <= m; ++jt) {
        const int j0 = jt * 64;

        #pragma unroll
        for (int cc = 0; cc < 2; ++cc) {
            const int r = cc * 32 + srow;
            async16(Kh + (size_t)(j0 + r) * DK_ + sunit * 8, &Kt[(cc * 32 + wv * 8) * 64]);
            async16(Vh + (size_t)r * S_ + j0 + sunit * 8,    &Vl[(cc * 32 + wv * 8) * 64]);
        }
        __syncthreads();

        short8 kb[4][2], vb[4][2];
        #pragma unroll
        for (int t = 0; t < 4; ++t)
            #pragma unroll
            for (int kh = 0; kh < 2; ++kh) {
                const int u = ((kh * 4 + quad) ^ (l16 & 7)) * 8;
                kb[t][kh] = load8(&Kt[(t * 16 + l16) * 64 + u]);
                vb[t][kh] = load8(&Vl[(t * 16 + l16) * 64 + u]);
            }

        f32x4 s[4];
        #pragma unroll
        for (int t = 0; t < 4; ++t) {
            f32x4 zz = {};
            zz = mfma16(qa0, kb[t][0], zz);
            s[t] = mfma16(qa1, kb[t][1], zz);
        }

        if (jt < m) {
            #pragma unroll
            for (int r = 0; r < 4; ++r)
                #pragma unroll
                for (int t = 0; t < 4; ++t)
                    lds_p[wv][quad * 4 + r][t * 16 + l16] =
                        __float2bfloat16(exp2f(c * s[t][r]));
        } else {
            #pragma unroll
            for (int r = 0; r < 4; ++r) {
                const int row = qr + quad * 4 + r;
                #pragma unroll
                for (int t = 0; t < 4; ++t) {
                    const float p = (j0 + t * 16 + l16 <= row) ? exp2f(c * s[t][r]) : 0.f;
                    lds_p[wv][quad * 4 + r][t * 16 + l16] = __float2bfloat16(p);
                }
            }
        }

        asm volatile("s_waitcnt lgkmcnt(0)" ::: "memory");
        const short8 pa0 = load8(&lds_p[wv][l16][quad * 8]);
        const short8 pa1 = load8(&lds_p[wv][l16][32 + quad * 8]);

        #pragma unroll
        for (int dt = 0; dt < 4; ++dt) {
            cacc[dt] = mfma16(pa0, vb[dt][0], cacc[dt]);
            cacc[dt] = mfma16(pa1, vb[dt][1], cacc[dt]);
        }
        lsum = mfma16(pa0, ones, lsum);
        lsum = mfma16(pa1, ones, lsum);

        __syncthreads();
    }

    const int bb = bh >> 4, hh = bh & 15;
    #pragma unroll
    for (int r = 0; r < 4; ++r) {
        const float inv = 1.0f / lsum[r];
        const int row = qr + quad * 4 + r;
        bf16* orow = ctx + (size_t)(bb * S_ + row) * D_ + hh * DK_;
        #pragma unroll
        for (int dt = 0; dt < 4; ++dt)
            orow[dt * 16 + l16] = __float2bfloat16(cacc[dt][r] * inv);
    }
}

extern "C" void kernel_launch(void* const* d_in, const int* in_sizes, int n_in,
                              void* d_out, int out_size, void* d_ws, size_t ws_size,
                              hipStream_t stream) {
    (void)in_sizes; (void)n_in; (void)out_size; (void)ws_size;
    const float* q  = (const float*)d_in[0];
    const float* k  = (const float*)d_in[1];
    const float* v  = (const float*)d_in[2];
    // d_in[3] = mask (int32 tril) -> causal analytically
    const float* wq = (const float*)d_in[4];
    const float* bq = (const float*)d_in[5];
    const float* wk = (const float*)d_in[6];
    const float* bk = (const float*)d_in[7];
    const float* wv = (const float*)d_in[8];
    const float* bv = (const float*)d_in[9];
    const float* wo = (const float*)d_in[10];
    const float* bo = (const float*)d_in[11];

    bf16* base = (bf16*)d_ws;
    bf16* Qb  = base;                         // (B,H,S,DK)
    bf16* Kb  = base + 1 * (size_t)SZX;
    bf16* Vt  = base + 2 * (size_t)SZX;       // (B,H,DK,S)
    bf16* ctx = base + 3 * (size_t)SZX;       // (B,S,D)
    bf16* xq  = base + 4 * (size_t)SZX;
    bf16* xk  = base + 5 * (size_t)SZX;
    bf16* xv  = base + 6 * (size_t)SZX;
    bf16* wqb = base + 7 * (size_t)SZX;
    bf16* wkb = wqb + 1 * (size_t)SZW;
    bf16* wvb = wqb + 2 * (size_t)SZW;
    bf16* wob = wqb + 3 * (size_t)SZW;

    CvtArgs ca;
    ca.src[0] = q;  ca.src[1] = k;  ca.src[2] = v;
    ca.src[3] = wq; ca.src[4] = wk; ca.src[5] = wv; ca.src[6] = wo;
    ca.dst[0] = xq;  ca.dst[1] = xk;  ca.dst[2] = xv;
    ca.dst[3] = wqb; ca.dst[4] = wkb; ca.dst[5] = wvb; ca.dst[6] = wob;
    cvt_kernel<<<8192, 256, 0, stream>>>(ca);

    ProjArgs pa;
    pa.X[0] = xq;  pa.X[1] = xk;  pa.X[2] = xv;
    pa.W[0] = wqb; pa.W[1] = wkb; pa.W[2] = wvb;
    pa.bias[0] = bq; pa.bias[1] = bk; pa.bias[2] = bv;
    pa.Y[0] = Qb; pa.Y[1] = Kb; pa.Y[2] = Vt;
    pa.mode[0] = 0; pa.mode[1] = 1; pa.mode[2] = 2;
    proj_kernel<128, 64><<<dim3(32, 16, 3), 256, 0, stream>>>(pa);

    attn_kernel<<<dim3(1024), 256, 0, stream>>>(Qb, Kb, Vt, ctx);

    ProjArgs po;
    po.X[0] = ctx; po.W[0] = wob; po.bias[0] = bo; po.Y[0] = d_out; po.mode[0] = 3;
    po.X[1] = ctx; po.W[1] = wob; po.bias[1] = bo; po.Y[1] = d_out; po.mode[1] = 3;
    po.X[2] = ctx; po.W[2] = wob; po.bias[2] = bo; po.Y[2] = d_out; po.mode[2] = 3;
    proj_kernel<64, 64><<<dim3(64, 16, 1), 256, 0, stream>>>(po);
}